// Round 1
// baseline (606.164 us; speedup 1.0000x reference)
//
#include <hip/hip_runtime.h>

#define SEQ_T   2048
#define BATCH_N 4096
#define LOG2E   1.4426950408889634f
#define PF      4   // x prefetch depth / unroll

__device__ __forceinline__ float bperm(int byteaddr, float v) {
    return __int_as_float(__builtin_amdgcn_ds_bpermute(byteaddr, __float_as_int(v)));
}

// Mapping: 16 lanes per batch element (chain). lane-in-group = gate row g (0..15,
// PyTorch order: rows 0-3 = i, 4-7 = f, 8-11 = g, 12-15 = o; unit u = g&3).
// Every lane redundantly maintains c,h of unit (g&3) so all cross-lane data is valid.
__global__ __launch_bounds__(256, 1) void lstm2_fused(
    const float* __restrict__ x,
    const float* __restrict__ Wih0, const float* __restrict__ Whh0,
    const float* __restrict__ bih0, const float* __restrict__ bhh0,
    const float* __restrict__ Wih1, const float* __restrict__ Whh1,
    const float* __restrict__ bih1, const float* __restrict__ bhh1,
    float* __restrict__ out)
{
    const int tid   = blockIdx.x * blockDim.x + threadIdx.x;
    const int lane  = threadIdx.x & 63;
    const int g     = tid & 15;          // gate row
    const int chain = tid >> 4;          // batch element 0..4095
    const int u     = g & 3;             // hidden unit
    const int role  = g >> 2;            // 0=i 1=f 2=g(cell) 3=o

    // Precomputed bpermute byte-addresses (wave-relative lane ids * 4).
    const int base = lane & ~15;
    int agath[4], adist[4];
#pragma unroll
    for (int k = 0; k < 4; ++k) {
        agath[k] = (base + 4*k + u) << 2;  // lane holding role k of unit u
        adist[k] = (base + k)     << 2;    // lane k holds h_k (role 0 lanes)
    }

    // Fold -log2e (sigmoid) / -2*log2e (tanh row) into weights+bias so the
    // per-step activation is exp2 -> rcp with zero extra scaling.
    const float srow = (role == 2) ? (-2.0f * LOG2E) : (-LOG2E);
    float wih0[4], whh0[4], wih1[4], whh1[4];
#pragma unroll
    for (int j = 0; j < 4; ++j) {
        wih0[j] = Wih0[g*4 + j] * srow;
        whh0[j] = Whh0[g*4 + j] * srow;
        wih1[j] = Wih1[g*4 + j] * srow;
        whh1[j] = Whh1[g*4 + j] * srow;
    }
    const float b0 = (bih0[g] + bhh0[g]) * srow;
    const float b1 = (bih1[g] + bhh1[g]) * srow;
    // act = ka * sigma + kb : identity for i,f,o ; 2s-1 (tanh) for g-row
    const float ka = (role == 2) ?  2.0f : 1.0f;
    const float kb = (role == 2) ? -1.0f : 0.0f;

    const float4* __restrict__ x4 = (const float4*)x;   // [T][B] float4

    // x prefetch ring (uniform address per 16-lane group; HW broadcasts)
    float4 xbuf[PF];
#pragma unroll
    for (int k = 0; k < PF; ++k) xbuf[k] = x4[k * BATCH_N + chain];

    float c0 = 0.f, c1 = 0.f;
    float H0[4] = {0.f, 0.f, 0.f, 0.f};   // layer0 h, distributed (natural order)
    float H1[4] = {0.f, 0.f, 0.f, 0.f};   // layer1 h, distributed

    for (int t = 0; t < SEQ_T; t += PF) {
#pragma unroll
        for (int k = 0; k < PF; ++k) {
            const float4 xv = xbuf[k];
            int tp = t + k + PF; tp = (tp < SEQ_T) ? tp : (SEQ_T - 1);
            xbuf[k] = x4[tp * BATCH_N + chain];

            // ---------------- layer 0 ----------------
            float p = b0;
            p = fmaf(wih0[0], xv.x,  p);
            p = fmaf(wih0[1], xv.y,  p);
            p = fmaf(wih0[2], xv.z,  p);
            p = fmaf(wih0[3], xv.w,  p);
            p = fmaf(whh0[0], H0[0], p);
            p = fmaf(whh0[1], H0[1], p);
            p = fmaf(whh0[2], H0[2], p);
            p = fmaf(whh0[3], H0[3], p);
            float e0  = __builtin_amdgcn_exp2f(p);
            float s0  = __builtin_amdgcn_rcpf(1.0f + e0);
            float a0  = fmaf(ka, s0, kb);
            float iv0 = bperm(agath[0], a0);
            float fv0 = bperm(agath[1], a0);
            float gv0 = bperm(agath[2], a0);
            float ov0 = bperm(agath[3], a0);
            c0 = fmaf(fv0, c0, iv0 * gv0);
            float ec0 = __builtin_amdgcn_exp2f(c0 * (-2.0f * LOG2E));
            float th0 = fmaf(2.0f, __builtin_amdgcn_rcpf(1.0f + ec0), -1.0f);
            float h0  = ov0 * th0;
#pragma unroll
            for (int j = 0; j < 4; ++j) H0[j] = bperm(adist[j], h0);

            // ---------------- layer 1 ----------------
            float q = b1;
            q = fmaf(wih1[0], H0[0], q);
            q = fmaf(wih1[1], H0[1], q);
            q = fmaf(wih1[2], H0[2], q);
            q = fmaf(wih1[3], H0[3], q);
            q = fmaf(whh1[0], H1[0], q);
            q = fmaf(whh1[1], H1[1], q);
            q = fmaf(whh1[2], H1[2], q);
            q = fmaf(whh1[3], H1[3], q);
            float e1  = __builtin_amdgcn_exp2f(q);
            float s1  = __builtin_amdgcn_rcpf(1.0f + e1);
            float a1  = fmaf(ka, s1, kb);
            float iv1 = bperm(agath[0], a1);
            float fv1 = bperm(agath[1], a1);
            float gv1 = bperm(agath[2], a1);
            float ov1 = bperm(agath[3], a1);
            c1 = fmaf(fv1, c1, iv1 * gv1);
            float ec1 = __builtin_amdgcn_exp2f(c1 * (-2.0f * LOG2E));
            float th1 = fmaf(2.0f, __builtin_amdgcn_rcpf(1.0f + ec1), -1.0f);
            float h1  = ov1 * th1;
#pragma unroll
            for (int j = 0; j < 4; ++j) H1[j] = bperm(adist[j], h1);

            // output: lanes with role==0 hold h1 of unit u -> out[t][chain][u]
            if (role == 0) {
                out[((t + k) * BATCH_N + chain) * 4 + u] = h1;
            }
        }
    }
}

extern "C" void kernel_launch(void* const* d_in, const int* in_sizes, int n_in,
                              void* d_out, int out_size, void* d_ws, size_t ws_size,
                              hipStream_t stream) {
    const float* x    = (const float*)d_in[0];
    const float* Wih0 = (const float*)d_in[1];
    const float* Whh0 = (const float*)d_in[2];
    const float* bih0 = (const float*)d_in[3];
    const float* bhh0 = (const float*)d_in[4];
    const float* Wih1 = (const float*)d_in[5];
    const float* Whh1 = (const float*)d_in[6];
    const float* bih1 = (const float*)d_in[7];
    const float* bhh1 = (const float*)d_in[8];
    float* out = (float*)d_out;

    // 4096 chains * 16 lanes = 65536 threads = 1024 waves = 1 wave per SIMD
    dim3 grid(256), block(256);
    hipLaunchKernelGGL(lstm2_fused, grid, block, 0, stream,
                       x, Wih0, Whh0, bih0, bhh0, Wih1, Whh1, bih1, bhh1, out);
}

// Round 2
// 473.514 us; speedup vs baseline: 1.2801x; 1.2801x over previous
//
#include <hip/hip_runtime.h>

#define SEQ_T   2048
#define BATCH_N 4096
#define LOG2E   1.4426950408889634f
#define PF      4   // x prefetch depth / unroll

// DPP quad_perm broadcast of quad-position k: ctrl = k*0x55
#define QP(v, ctrl) __int_as_float(__builtin_amdgcn_mov_dpp(__float_as_int(v), (ctrl), 0xF, 0xF, true))
// ds_swizzle BitMode: src = ((lane & and) | or) ^ xor ; offset = (xor<<10)|(or<<5)|and
// and=0x13 keeps role bits [1:0] + 16-group bit [4]; or=4j selects unit j's quad.
#define SWZ(v, off) __int_as_float(__builtin_amdgcn_ds_swizzle(__float_as_int(v), (off)))

// Mapping: 16 lanes per chain, UNIT-MAJOR: lane-in-16 = 4*u + r
// (u = hidden unit 0..3, r = role 0=i 1=f 2=g 3=o). PyTorch weight row = r*4+u.
// Gate gather (all roles of my unit) = intra-quad -> DPP quad_perm (no DS).
// h distribute (h_j from quad j) = 4x ds_swizzle, one DS round per layer.
__global__ __launch_bounds__(256, 1) void lstm2_fused(
    const float* __restrict__ x,
    const float* __restrict__ Wih0, const float* __restrict__ Whh0,
    const float* __restrict__ bih0, const float* __restrict__ bhh0,
    const float* __restrict__ Wih1, const float* __restrict__ Whh1,
    const float* __restrict__ bih1, const float* __restrict__ bhh1,
    float* __restrict__ out)
{
    const int tid   = blockIdx.x * blockDim.x + threadIdx.x;
    const int g16   = tid & 15;
    const int u     = g16 >> 2;          // hidden unit (quad index)
    const int r     = g16 & 3;           // role 0=i 1=f 2=g 3=o
    const int chain = tid >> 4;          // batch element
    const int row   = r * 4 + u;         // PyTorch gate-row index

    // Fold -log2e (sigmoid) / -2log2e (tanh row) into weights & bias.
    const float srow = (r == 2) ? (-2.0f * LOG2E) : (-LOG2E);
    float wih0[4], whh0[4], wih1[4], whh1[4];
#pragma unroll
    for (int j = 0; j < 4; ++j) {
        wih0[j] = Wih0[row * 4 + j] * srow;
        whh0[j] = Whh0[row * 4 + j] * srow;
        wih1[j] = Wih1[row * 4 + j] * srow;
        whh1[j] = Whh1[row * 4 + j] * srow;
    }
    const float b0 = (bih0[row] + bhh0[row]) * srow;
    const float b1 = (bih1[row] + bhh1[row]) * srow;
    const float ka = (r == 2) ?  2.0f : 1.0f;   // act = ka*sigma + kb
    const float kb = (r == 2) ? -1.0f : 0.0f;

    const float4* __restrict__ x4 = (const float4*)x;   // [T][B] as float4

    float4 xbuf[PF];
#pragma unroll
    for (int k = 0; k < PF; ++k) xbuf[k] = x4[k * BATCH_N + chain];

    float c0 = 0.f, c1 = 0.f;
    float H0[4] = {0.f, 0.f, 0.f, 0.f};
    float H1[4] = {0.f, 0.f, 0.f, 0.f};

    // One LSTM cell step for this lane's (unit,role); returns h of my unit.
    auto cell = [&](float i0, float i1, float i2, float i3,
                    const float* wih, const float* whh, float bb,
                    float& c, const float* H) -> float {
        float p = bb;
        p = fmaf(wih[0], i0, p);
        p = fmaf(wih[1], i1, p);
        p = fmaf(wih[2], i2, p);
        p = fmaf(wih[3], i3, p);
        p = fmaf(whh[0], H[0], p);
        p = fmaf(whh[1], H[1], p);
        p = fmaf(whh[2], H[2], p);
        p = fmaf(whh[3], H[3], p);
        float s  = __builtin_amdgcn_rcpf(1.0f + __builtin_amdgcn_exp2f(p));
        float a  = fmaf(ka, s, kb);       // my role's activated gate
        float iv = QP(a, 0x00);           // role 0 of my quad
        float fv = QP(a, 0x55);           // role 1
        float gv = QP(a, 0xAA);           // role 2
        float ov = QP(a, 0xFF);           // role 3
        c = fmaf(fv, c, iv * gv);
        float ec = __builtin_amdgcn_exp2f(c * (-2.0f * LOG2E));
        float th = fmaf(2.0f, __builtin_amdgcn_rcpf(1.0f + ec), -1.0f);
        return ov * th;
    };

    for (int t = 0; t < SEQ_T; t += PF) {
#pragma unroll
        for (int k = 0; k < PF; ++k) {
            const float4 xv = xbuf[k];
            int tp = t + k + PF; tp = (tp < SEQ_T) ? tp : (SEQ_T - 1);
            xbuf[k] = x4[tp * BATCH_N + chain];

            // ---- layer 0 ----
            float h0 = cell(xv.x, xv.y, xv.z, xv.w, wih0, whh0, b0, c0, H0);
            H0[0] = SWZ(h0, 0x0013);   // h of unit 0 (src = group|0*4|r)
            H0[1] = SWZ(h0, 0x0093);   // unit 1
            H0[2] = SWZ(h0, 0x0113);   // unit 2
            H0[3] = SWZ(h0, 0x0193);   // unit 3

            // ---- layer 1 ----
            float h1 = cell(H0[0], H0[1], H0[2], H0[3], wih1, whh1, b1, c1, H1);
            H1[0] = SWZ(h1, 0x0013);
            H1[1] = SWZ(h1, 0x0093);
            H1[2] = SWZ(h1, 0x0113);
            H1[3] = SWZ(h1, 0x0193);

            if (r == 0) {
                out[((t + k) * BATCH_N + chain) * 4 + u] = h1;
            }
        }
    }
}

extern "C" void kernel_launch(void* const* d_in, const int* in_sizes, int n_in,
                              void* d_out, int out_size, void* d_ws, size_t ws_size,
                              hipStream_t stream) {
    const float* x    = (const float*)d_in[0];
    const float* Wih0 = (const float*)d_in[1];
    const float* Whh0 = (const float*)d_in[2];
    const float* bih0 = (const float*)d_in[3];
    const float* bhh0 = (const float*)d_in[4];
    const float* Wih1 = (const float*)d_in[5];
    const float* Whh1 = (const float*)d_in[6];
    const float* bih1 = (const float*)d_in[7];
    const float* bhh1 = (const float*)d_in[8];
    float* out = (float*)d_out;

    // 4096 chains * 16 lanes = 1024 waves = 1 wave per SIMD machine-wide
    dim3 grid(256), block(256);
    hipLaunchKernelGGL(lstm2_fused, grid, block, 0, stream,
                       x, Wih0, Whh0, bih0, bhh0, Wih1, Whh1, bih1, bhh1, out);
}

// Round 3
// 400.357 us; speedup vs baseline: 1.5141x; 1.1827x over previous
//
#include <hip/hip_runtime.h>

#define SEQ_T   2048
#define BATCH_N 4096
#define LOG2E   1.4426950408889634f
#define PF      8   // x prefetch depth / unroll

// DPP mov: quad_perm = 0x00..0xFF, ROW_MIRROR = 0x140, ROW_HALF_MIRROR = 0x141
#define DPPF(v, ctrl) __int_as_float(__builtin_amdgcn_mov_dpp(__float_as_int(v), (ctrl), 0xF, 0xF, true))

// Mapping: 16 lanes per chain, UNIT-MAJOR: lane-in-16 = 4*u + r
// (u = hidden unit = quad index, r = role 0=i 1=f 2=g 3=o). PyTorch row = r*4+u.
// Gate gather  : intra-quad quad_perm DPP.
// h distribute : ROW_HALF_MIRROR -> h_{u^1}; ROW_MIRROR -> h_{u^3};
//                mirror(half_mirror) -> h_{u^2}.  All VALU, zero DS ops.
// Weights are pre-permuted per lane into u-relative order: w[d] = W[row][u^d].
__global__ __launch_bounds__(256, 1) void lstm2_fused(
    const float* __restrict__ x,
    const float* __restrict__ Wih0, const float* __restrict__ Whh0,
    const float* __restrict__ bih0, const float* __restrict__ bhh0,
    const float* __restrict__ Wih1, const float* __restrict__ Whh1,
    const float* __restrict__ bih1, const float* __restrict__ bhh1,
    float* __restrict__ out)
{
    const int tid   = blockIdx.x * blockDim.x + threadIdx.x;
    const int g16   = tid & 15;
    const int u     = g16 >> 2;          // hidden unit (quad)
    const int r     = g16 & 3;           // role 0=i 1=f 2=g 3=o
    const int chain = tid >> 4;          // batch element
    const int row   = r * 4 + u;         // PyTorch gate-row index

    // Fold -log2e (sigmoid) / -2log2e (tanh row) into weights & bias.
    const float srow = (r == 2) ? (-2.0f * LOG2E) : (-LOG2E);
    float wih0[4], whh0[4], wih1[4], whh1[4];
#pragma unroll
    for (int d = 0; d < 4; ++d) {
        wih0[d] = Wih0[row * 4 + d]       * srow;  // natural order (x input)
        whh0[d] = Whh0[row * 4 + (u ^ d)] * srow;  // u-relative order
        wih1[d] = Wih1[row * 4 + (u ^ d)] * srow;  // u-relative order
        whh1[d] = Whh1[row * 4 + (u ^ d)] * srow;  // u-relative order
    }
    const float b0 = (bih0[row] + bhh0[row]) * srow;
    const float b1 = (bih1[row] + bhh1[row]) * srow;
    const float ka = (r == 2) ?  2.0f : 1.0f;   // act = ka*sigma + kb
    const float kb = (r == 2) ? -1.0f : 0.0f;

    const float4* __restrict__ x4 = (const float4*)x;   // [T][B] as float4
    float4* __restrict__ out4 = (float4*)out;

    float4 xbuf[PF];
#pragma unroll
    for (int k = 0; k < PF; ++k) xbuf[k] = x4[k * BATCH_N + chain];

    float c0 = 0.f, c1 = 0.f;
    // h-state in u-relative order: hX = h_{u}, hXa = h_{u^1}, hXb = h_{u^2}, hXc = h_{u^3}
    float h0 = 0.f, h0a = 0.f, h0b = 0.f, h0c = 0.f;
    float h1 = 0.f, h1a = 0.f, h1b = 0.f, h1c = 0.f;

    for (int t = 0; t < SEQ_T; t += PF) {
#pragma unroll
        for (int k = 0; k < PF; ++k) {
            const float4 xv = xbuf[k];
            int tp = t + k + PF; tp = (tp < SEQ_T) ? tp : (SEQ_T - 1);
            xbuf[k] = x4[tp * BATCH_N + chain];

            // ---------------- layer 0 ----------------
            // input-dot off the critical path (xv known PF steps ahead)
            float px0 = fmaf(wih0[0], xv.x,
                        fmaf(wih0[1], xv.y,
                        fmaf(wih0[2], xv.z,
                        fmaf(wih0[3], xv.w, b0))));
            // recurrent dot; h0b (2 DPP deep) consumed last
            float p0 = fmaf(whh0[2], h0b,
                       fmaf(whh0[3], h0c,
                       fmaf(whh0[1], h0a,
                       fmaf(whh0[0], h0, px0))));
            float s0 = __builtin_amdgcn_rcpf(1.0f + __builtin_amdgcn_exp2f(p0));
            float a0 = fmaf(ka, s0, kb);
            float iv0 = DPPF(a0, 0x00);
            float fv0 = DPPF(a0, 0x55);
            float gv0 = DPPF(a0, 0xAA);
            float ov0 = DPPF(a0, 0xFF);
            c0 = fmaf(fv0, c0, iv0 * gv0);
            float ec0 = __builtin_amdgcn_exp2f(c0 * (-2.0f * LOG2E));
            float th0 = fmaf(2.0f, __builtin_amdgcn_rcpf(1.0f + ec0), -1.0f);
            h0  = ov0 * th0;               // uniform within my quad
            h0a = DPPF(h0,  0x141);        // h_{u^1}
            h0c = DPPF(h0,  0x140);        // h_{u^3}
            h0b = DPPF(h0a, 0x140);        // h_{u^2}

            // ---------------- layer 1 ----------------
            float px1 = fmaf(wih1[2], h0b,
                        fmaf(wih1[3], h0c,
                        fmaf(wih1[1], h0a,
                        fmaf(wih1[0], h0, b1))));
            float p1 = fmaf(whh1[2], h1b,
                       fmaf(whh1[3], h1c,
                       fmaf(whh1[1], h1a,
                       fmaf(whh1[0], h1, px1))));
            float s1 = __builtin_amdgcn_rcpf(1.0f + __builtin_amdgcn_exp2f(p1));
            float a1 = fmaf(ka, s1, kb);
            float iv1 = DPPF(a1, 0x00);
            float fv1 = DPPF(a1, 0x55);
            float gv1 = DPPF(a1, 0xAA);
            float ov1 = DPPF(a1, 0xFF);
            c1 = fmaf(fv1, c1, iv1 * gv1);
            float ec1 = __builtin_amdgcn_exp2f(c1 * (-2.0f * LOG2E));
            float th1 = fmaf(2.0f, __builtin_amdgcn_rcpf(1.0f + ec1), -1.0f);
            h1  = ov1 * th1;
            h1a = DPPF(h1,  0x141);
            h1c = DPPF(h1,  0x140);
            h1b = DPPF(h1a, 0x140);

            // lane g16==0 has u==0: (h1,h1a,h1b,h1c) = (h_0,h_1,h_2,h_3)
            if (g16 == 0) {
                out4[(t + k) * BATCH_N + chain] = make_float4(h1, h1a, h1b, h1c);
            }
        }
    }
}

extern "C" void kernel_launch(void* const* d_in, const int* in_sizes, int n_in,
                              void* d_out, int out_size, void* d_ws, size_t ws_size,
                              hipStream_t stream) {
    const float* x    = (const float*)d_in[0];
    const float* Wih0 = (const float*)d_in[1];
    const float* Whh0 = (const float*)d_in[2];
    const float* bih0 = (const float*)d_in[3];
    const float* bhh0 = (const float*)d_in[4];
    const float* Wih1 = (const float*)d_in[5];
    const float* Whh1 = (const float*)d_in[6];
    const float* bih1 = (const float*)d_in[7];
    const float* bhh1 = (const float*)d_in[8];
    float* out = (float*)d_out;

    // 4096 chains * 16 lanes = 1024 waves = 1 wave per SIMD machine-wide
    dim3 grid(256), block(256);
    hipLaunchKernelGGL(lstm2_fused, grid, block, 0, stream,
                       x, Wih0, Whh0, bih0, bhh0, Wih1, Whh1, bih1, bhh1, out);
}

// Round 4
// 362.199 us; speedup vs baseline: 1.6736x; 1.1053x over previous
//
#include <hip/hip_runtime.h>

#define SEQ_T   2048
#define BATCH_N 4096
#define LOG2E   1.4426950408889634f
#define PF      8

typedef float v2f __attribute__((ext_vector_type(2)));

// DPP mov: quad_perm = 0x00..0xFF, ROW_MIRROR = 0x140, ROW_HALF_MIRROR = 0x141
#define DPPF(v, ctrl) __int_as_float(__builtin_amdgcn_mov_dpp(__float_as_int(v), (ctrl), 0xF, 0xF, true))

static __device__ __forceinline__ v2f pkfma(v2f a, v2f b, v2f c) {
#if __has_builtin(__builtin_elementwise_fma)
    return __builtin_elementwise_fma(a, b, c);
#else
    v2f r; r.x = fmaf(a.x, b.x, c.x); r.y = fmaf(a.y, b.y, c.y); return r;
#endif
}
static __device__ __forceinline__ v2f exp2v(v2f a) {
    v2f r; r.x = __builtin_amdgcn_exp2f(a.x); r.y = __builtin_amdgcn_exp2f(a.y); return r;
}
static __device__ __forceinline__ v2f rcpv(v2f a) {
    v2f r; r.x = __builtin_amdgcn_rcpf(a.x); r.y = __builtin_amdgcn_rcpf(a.y); return r;
}

// 16 lanes per chain, UNIT-MAJOR: lane-in-16 = 4*u + r (u=unit=quad, r=role).
// PyTorch row = r*4+u. Gate gather: quad_perm DPP. h distribute: mirror DPPs.
// LAYER PACKING: float2 lanes = (layer0 @ step k, layer1 @ step k-1).
// Recurrent pairs (hh*, cc) hold exactly what each half needs -> zero-cost pack.
__global__ __launch_bounds__(256, 1) void lstm2_fused(
    const float* __restrict__ x,
    const float* __restrict__ Wih0, const float* __restrict__ Whh0,
    const float* __restrict__ bih0, const float* __restrict__ bhh0,
    const float* __restrict__ Wih1, const float* __restrict__ Whh1,
    const float* __restrict__ bih1, const float* __restrict__ bhh1,
    float* __restrict__ out)
{
    const int tid   = blockIdx.x * blockDim.x + threadIdx.x;
    const int g16   = tid & 15;
    const int u     = g16 >> 2;          // hidden unit (quad)
    const int r     = g16 & 3;           // role 0=i 1=f 2=g 3=o
    const int chain = tid >> 4;          // batch element
    const int row   = r * 4 + u;         // PyTorch gate-row index

    // Fold -log2e (sigmoid) / -2log2e (tanh row) into weights & bias.
    const float srow = (r == 2) ? (-2.0f * LOG2E) : (-LOG2E);
    float wih0[4], whh0[4], wih1[4], whh1[4];
#pragma unroll
    for (int d = 0; d < 4; ++d) {
        wih0[d] = Wih0[row * 4 + d]       * srow;  // natural order (x input)
        whh0[d] = Whh0[row * 4 + (u ^ d)] * srow;  // u-relative order
        wih1[d] = Wih1[row * 4 + (u ^ d)] * srow;
        whh1[d] = Whh1[row * 4 + (u ^ d)] * srow;
    }
    const float b0 = (bih0[row] + bhh0[row]) * srow;
    const float b1 = (bih1[row] + bhh1[row]) * srow;
    const float ka = (r == 2) ?  2.0f : 1.0f;   // act = ka*sigma + kb
    const float kb = (r == 2) ? -1.0f : 0.0f;

    const v2f kaa  = {ka, ka};
    const v2f kbb  = {kb, kb};
    const v2f onev = {1.0f, 1.0f};
    const v2f two2 = {2.0f, 2.0f};
    const v2f neg1 = {-1.0f, -1.0f};
    const v2f m2l  = {-2.0f * LOG2E, -2.0f * LOG2E};

    const float4* __restrict__ x4 = (const float4*)x;   // [T][B] as float4
    float4* __restrict__ out4 = (float4*)out;

    // ---- peel: layer0 step 0 (h0(-1)=0, c0(-1)=0); hi halves start at 0 ----
    const float4 x0v = x4[chain];
    float p = fmaf(wih0[0], x0v.x, fmaf(wih0[1], x0v.y,
              fmaf(wih0[2], x0v.z, fmaf(wih0[3], x0v.w, b0))));
    float s = __builtin_amdgcn_rcpf(1.0f + __builtin_amdgcn_exp2f(p));
    float a = fmaf(ka, s, kb);
    float iv = DPPF(a, 0x00);
    float gv = DPPF(a, 0xAA);
    float ov = DPPF(a, 0xFF);
    float c0p = iv * gv;                               // f*0 term dropped
    float ec = __builtin_amdgcn_exp2f(c0p * (-2.0f * LOG2E));
    float th = fmaf(2.0f, __builtin_amdgcn_rcpf(1.0f + ec), -1.0f);
    float h0p = ov * th;

    v2f cc  = {c0p, 0.0f};
    v2f hh  = {h0p, 0.0f};
    v2f hha = {DPPF(h0p, 0x141), 0.0f};     // h_{u^1}
    v2f hhc = {DPPF(h0p, 0x140), 0.0f};     // h_{u^3}
    v2f hhb = {DPPF(hha.x, 0x140), 0.0f};   // h_{u^2}

    // ---- x prefetch ring: x(1..PF) ----
    float4 xbuf[PF];
#pragma unroll
    for (int i = 0; i < PF; ++i) xbuf[i] = x4[(1 + i) * BATCH_N + chain];

    // ---- main loop: iteration k does L0 step k (lo) and L1 step k-1 (hi) ----
    for (int kk = 1; kk <= SEQ_T; kk += PF) {
#pragma unroll
        for (int q = 0; q < PF; ++q) {
            const int k = kk + q;
            const float4 xv = xbuf[q];
            int tp = k + PF; tp = (tp > SEQ_T - 1) ? (SEQ_T - 1) : tp;
            xbuf[q] = x4[tp * BATCH_N + chain];

            // off-critical-path accumulators (operands from previous iter)
            float accx = fmaf(wih0[0], xv.x, fmaf(wih0[1], xv.y,
                         fmaf(wih0[2], xv.z, fmaf(wih0[3], xv.w, b0))));
            float accy = fmaf(whh1[0], hh.y, fmaf(whh1[1], hha.y,
                         fmaf(whh1[2], hhb.y, fmaf(whh1[3], hhc.y, b1))));
            // critical: h0(k-1) terms feed BOTH halves
            float ax = fmaf(whh0[0], hh.x, fmaf(whh0[1], hha.x,
                       fmaf(whh0[2], hhb.x, fmaf(whh0[3], hhc.x, accx))));
            float ay = fmaf(wih1[0], hh.x, fmaf(wih1[1], hha.x,
                       fmaf(wih1[2], hhb.x, fmaf(wih1[3], hhc.x, accy))));
            v2f acc = {ax, ay};

            // packed sigma/tanh-gate activation
            v2f e  = exp2v(acc);
            v2f sr = rcpv(e + onev);
            v2f a2 = pkfma(kaa, sr, kbb);

            // gate gather (intra-quad), per 32-bit half
            v2f ii = {DPPF(a2.x, 0x00), DPPF(a2.y, 0x00)};
            v2f ff = {DPPF(a2.x, 0x55), DPPF(a2.y, 0x55)};
            v2f gg = {DPPF(a2.x, 0xAA), DPPF(a2.y, 0xAA)};
            v2f oo = {DPPF(a2.x, 0xFF), DPPF(a2.y, 0xFF)};

            cc = pkfma(ff, cc, ii * gg);
            v2f ez  = exp2v(cc * m2l);
            v2f thv = pkfma(two2, rcpv(ez + onev), neg1);
            hh = oo * thv;

            // distribute h to u-relative slots, per half
            hha = (v2f){DPPF(hh.x, 0x141), DPPF(hh.y, 0x141)};
            hhc = (v2f){DPPF(hh.x, 0x140), DPPF(hh.y, 0x140)};
            hhb = (v2f){DPPF(hha.x, 0x140), DPPF(hha.y, 0x140)};

            // hi half just finished h1(k-1); lane g16==0 holds natural order
            if (g16 == 0) {
                out4[(k - 1) * BATCH_N + chain] =
                    make_float4(hh.y, hha.y, hhb.y, hhc.y);
            }
        }
    }
}

extern "C" void kernel_launch(void* const* d_in, const int* in_sizes, int n_in,
                              void* d_out, int out_size, void* d_ws, size_t ws_size,
                              hipStream_t stream) {
    const float* x    = (const float*)d_in[0];
    const float* Wih0 = (const float*)d_in[1];
    const float* Whh0 = (const float*)d_in[2];
    const float* bih0 = (const float*)d_in[3];
    const float* bhh0 = (const float*)d_in[4];
    const float* Wih1 = (const float*)d_in[5];
    const float* Whh1 = (const float*)d_in[6];
    const float* bih1 = (const float*)d_in[7];
    const float* bhh1 = (const float*)d_in[8];
    float* out = (float*)d_out;

    // 4096 chains * 16 lanes = 1024 waves = 1 wave per SIMD machine-wide
    dim3 grid(256), block(256);
    hipLaunchKernelGGL(lstm2_fused, grid, block, 0, stream,
                       x, Wih0, Whh0, bih0, bhh0, Wih1, Whh1, bih1, bhh1, out);
}